// Round 18
// baseline (185911.523 us; speedup 1.0000x reference)
//
#include <hip/hip_runtime.h>
#include <hip/hip_bf16.h>
#include <stdint.h>

#define SEQ     8192
#define DIM     2048
#define HID     1024
#define NWG     256
#define CPW     8      // columns per workgroup (fused/mid layers)

typedef unsigned long long u64;
typedef __attribute__((ext_vector_type(2))) unsigned int u32x2;

// ===== Algebraic fold (R12) + single-writer lines (R13) + arrival-order
// compute (R16) + per-wave direct publish (R17) =====
//
// a0(t) = XC(t) + relu(a3(t-1)) @ G ;  a_{i+1} = relu(a_i)@Wmid_i + b
// outputs[t] = relu(a3(t))@WfO+bfO (phase A of step t+1, off critical path)
// G = Wf[:,:1024]@W0[1024:,:] (f32), XC = x@W0[:1024,:]+b0(+bf@W0h for t>0).
// 4 exchanges/step (algebraic minimum; ReLU blocks further folding).
//
// R17 buffer layout: each a-buffer = 1024 lines x 64 B. Global wave
// w = wg*4+wave owns line w: its 2 columns (cols 2w, 2w+1) as ONE tagged 8B
// pair {bf16|tag<<16}x2 at line start, bytes 8..63 pad. After its reduce,
// each wave's lane0 fires one 8B agent store into its OWN line:
//  - zero line sharing (R13's invariant, now 1 writer AND 1 store per line)
//  - no LDS gather hop: publish no longer waits for sibling waves via sG,
//    and wave0 is no longer the designated gatherer/straggler.
// Consumer lane L of wave v needs cols [v*512+L*8, +8) = lines
// v*256+L*4+{0..3}: poll 4x global_load_dwordx2 (offsets 0/64/128/192) ->
// vmcnt(0)+sched_barrier -> check 8 tags -> s_sleep. 4 req/sample = 2x R13
// (R15 collapse was 8x with no sleep; this stays inside the budget).
//
// Safety (tag chain, unchanged logic):
//  - tags monotone (max 4*8191+4+1 < 2^16); ready iff dword >= tag<<16
//    (tag==T-1 caps at (T<<16)-1: value bits cannot fake readiness).
//  - a wave's publish data-depends on its poll loads (drained) => observing
//    a tag implies the producer finished reading its own inputs.
//  - buffer reuse: a-buffer written at step t+1 only after that wave's
//    phase chain consumed all step-t tags, which transitively happens-after
//    every wave's step-t read of that buffer (4-phase spacing). Consumers
//    cannot observe newer-than-target tags (monotone >= + induction).
//  - sAct/sflag parity reuse at p+2: guarded by the same global chain (every
//    WG's staging each phase polls lines covering ALL waves).
//
// XC hosting: XC[t] in OUT at outputs-row t+2 (overwritten 12 phases after
// consumption, tag-chain ordered). Tail rows in ws.
// ws: 0:a0b 65536:a1b 131072:a2b 196608:a3b (64KB each; memset=0 => a3
// "ready for t=0" with zeros == H(-1)=0)  262144: XC tail  270336: hb
// 278528: Gt f32 (16MB)

__device__ __forceinline__ uint16_t f2bf(float f) {
  union { float f; uint32_t u; } v; v.f = f;
  uint32_t r = v.u + 0x7FFFu + ((v.u >> 16) & 1u);   // round-to-nearest-even
  return (uint16_t)(r >> 16);
}
__device__ __forceinline__ float bf2f(uint16_t u) {
  union { uint32_t u; float f; } v; v.u = ((uint32_t)u) << 16; return v.f;
}
__device__ __forceinline__ void cstore64(u64* p, u64 v) {
  __hip_atomic_store(p, v, __ATOMIC_RELAXED, __HIP_MEMORY_SCOPE_AGENT);
}
__device__ __forceinline__ u64 pack2(float v0, float v1, uint32_t tag) {
  const uint32_t w0 = (uint32_t)f2bf(v0) | (tag << 16);
  const uint32_t w1 = (uint32_t)f2bf(v1) | (tag << 16);
  return ((u64)w1 << 32) | (u64)w0;
}
__device__ __forceinline__ u32x2 cload64c(const void* p) {
  u32x2 r;
  asm volatile("global_load_dwordx2 %0, %1, off sc0 sc1"
               : "=v"(r) : "v"(p) : "memory");
  return r;
}
__device__ __forceinline__ void vm_drain() {
  asm volatile("s_waitcnt vmcnt(0)" ::: "memory");
  __builtin_amdgcn_sched_barrier(0);
}

// Poll this lane's 4 lines (its 8 columns) of an a-buffer; decode (relu)
// into the LDS staging quarter. R5-proven shape: issue -> drain -> check ->
// sleep; 4 requests/sample.
__device__ __forceinline__ void poll_stage(const uint32_t* __restrict__ buf,
                                           int wave, int lane, uint32_t thr,
                                           float* __restrict__ d) {
  const uint32_t* p = buf + (size_t)(wave * 256 + lane * 4) * 16;
  u32x2 a, b, c, e;
  for (;;) {
    a = cload64c(p);
    b = cload64c(p + 16);
    c = cload64c(p + 32);
    e = cload64c(p + 48);
    vm_drain();
    bool ok = (a[0] >= thr) & (a[1] >= thr) & (b[0] >= thr) & (b[1] >= thr) &
              (c[0] >= thr) & (c[1] >= thr) & (e[0] >= thr) & (e[1] >= thr);
    if (__all(ok)) break;
    __builtin_amdgcn_s_sleep(1);
  }
  d[0] = fmaxf(__uint_as_float(a[0] << 16), 0.f);
  d[1] = fmaxf(__uint_as_float(a[1] << 16), 0.f);
  d[2] = fmaxf(__uint_as_float(b[0] << 16), 0.f);
  d[3] = fmaxf(__uint_as_float(b[1] << 16), 0.f);
  d[4] = fmaxf(__uint_as_float(c[0] << 16), 0.f);
  d[5] = fmaxf(__uint_as_float(c[1] << 16), 0.f);
  d[6] = fmaxf(__uint_as_float(e[0] << 16), 0.f);
  d[7] = fmaxf(__uint_as_float(e[1] << 16), 0.f);
}

// spin on an LDS quarter-flag until it reaches `want` (monotone)
__device__ __forceinline__ void lds_spin(uint32_t* f, uint32_t want) {
  while (__hip_atomic_load(f, __ATOMIC_RELAXED,
                           __HIP_MEMORY_SCOPE_WORKGROUP) < want) {}
  asm volatile("" ::: "memory");
  __builtin_amdgcn_sched_barrier(0);
}

// ---------------- precompute kernels (one-time, parallel) ----------------
__global__ void k_hb(const float* __restrict__ W0, const float* __restrict__ b0,
                     const float* __restrict__ bfv, float* __restrict__ hb) {
  const int j = blockIdx.x * 256 + threadIdx.x;
  float acc = b0[j];
  for (int m = 0; m < HID; ++m)
    acc = fmaf(bfv[m], W0[(size_t)(HID + m) * DIM + j], acc);
  hb[j] = acc;
}

__global__ void k_G(const float* __restrict__ W0, const float* __restrict__ Wf,
                    float* __restrict__ Gt) {
  const int j = blockIdx.x * 16 + threadIdx.x;     // a0 column
  const int k = blockIdx.y * 16 + threadIdx.y;     // a3 index
  float acc = 0.f;
  for (int m = 0; m < HID; ++m)
    acc = fmaf(Wf[(size_t)k * DIM + m], W0[(size_t)(HID + m) * DIM + j], acc);
  Gt[(size_t)j * DIM + k] = acc;
}

__global__ void k_XC(const float* __restrict__ x, const float* __restrict__ W0,
                     const float* __restrict__ b0, const float* __restrict__ hb,
                     float* __restrict__ out, uint16_t* __restrict__ xct) {
  const int j = blockIdx.x * 16 + threadIdx.x;
  const int t = blockIdx.y * 16 + threadIdx.y;
  float acc = 0.f;
  for (int m = 0; m < HID; ++m)
    acc = fmaf(x[(size_t)t * HID + m], W0[(size_t)m * DIM + j], acc);
  acc += (t > 0) ? hb[j] : b0[j];
  const uint16_t v = f2bf(acc);
  if (t <= SEQ - 3) ((uint16_t*)(out + HID + (size_t)(t + 2) * HID))[j] = v;
  else              xct[(size_t)(t - (SEQ - 2)) * DIM + j] = v;
}

// ---------------- persistent 4-phase recurrence kernel ----------------
__global__ void __launch_bounds__(256, 1)
rnn_persist(const float* __restrict__ Wmid, const float* __restrict__ bmid,
            const float* __restrict__ Wf, const float* __restrict__ bfv,
            float* __restrict__ out, uint32_t* __restrict__ a0b,
            uint32_t* __restrict__ a1b, uint32_t* __restrict__ a2b,
            uint32_t* __restrict__ a3b, const float* __restrict__ Gt,
            const uint16_t* __restrict__ xct)
{
  __shared__ uint16_t wlds[3 * CPW * DIM];   // Wmid 0..2 slices, 96 KiB
  __shared__ uint16_t wflds[4 * DIM];        // Wf out-col slice, 16 KiB
  __shared__ float    sAct[2][DIM];          // parity double-buffered, 16 KiB
  __shared__ uint32_t sflag[2][4];           // parity quarter-ready flags

  const int tid  = threadIdx.x;
  const int wg   = blockIdx.x;
  const int wave = tid >> 6;
  const int lane = tid & 63;

  const int cidx0 = wave * 2;
  const int col0  = wg * CPW + cidx0;        // fused/mid layer columns
  const int col1  = col0 + 1;
  const int ocol  = wg * 4 + wave;           // out_seq / hidden column
  const size_t myline = (size_t)(wg * 4 + wave) * 8;   // u64 index of own line

  // ---- stage Wmid slices (bf16) into LDS ----
  for (int i = tid; i < 3 * CPW * DIM; i += 256) {
    const int l = i >> 14;
    const int r = i & 16383;
    const int k = r >> 3;
    const int c = r & 7;
    wlds[(l * CPW + c) * DIM + k] =
        f2bf(Wmid[(size_t)l * DIM * DIM + (size_t)k * DIM + (wg * CPW + c)]);
  }
  // ---- stage Wf out-columns (4 per WG) into LDS ----
  for (int i = tid; i < 4 * DIM; i += 256) {
    const int w = i >> 11;
    const int k = i & 2047;
    wflds[w * DIM + k] = f2bf(Wf[(size_t)k * DIM + HID + wg * 4 + w]);
  }
  // ---- fused-layer G columns into registers, own-quarter-relative order:
  //      gf[qi*2+jj] covers k-block (2*((wave+qi)&3)+jj) (compile-time idx) --
  float4 gf0[8], gf1[8];
  #pragma unroll
  for (int qi = 0; qi < 4; ++qi) {
    const int q = (wave + qi) & 3;
    #pragma unroll
    for (int jj = 0; jj < 2; ++jj) {
      const int k = (2 * q + jj) * 256 + lane * 4;
      gf0[qi * 2 + jj] = *(const float4*)(Gt + (size_t)col0 * DIM + k);
      gf1[qi * 2 + jj] = *(const float4*)(Gt + (size_t)col1 * DIM + k);
    }
  }
  if (tid < 8) sflag[tid >> 2][tid & 3] = 0;
  __syncthreads();   // weights + slot init visible

  float bm0[3], bm1[3];
  #pragma unroll
  for (int l = 0; l < 3; ++l) {
    bm0[l] = bmid[l * DIM + col0];
    bm1[l] = bmid[l * DIM + col1];
  }
  const float bo = bfv[HID + ocol];

  uint32_t ph = 0;   // phase index = 4t + l

  for (int t = 0; t < SEQ; ++t) {
    // ============ phase A: fused layer + out_seq(t-1) ============
    {
      const int par = (int)(ph & 1u);
      float* __restrict__ sa = sAct[par];
      const uint32_t want = ph + 1u;
      const uint16_t* xcrow = (t <= SEQ - 3)
          ? (const uint16_t*)(out + HID + (size_t)(t + 2) * HID)
          : (xct + (size_t)(t - (SEQ - 2)) * DIM);
      const uint32_t xcw = *(const uint32_t*)(xcrow + col0);

      poll_stage(a3b, wave, lane, (4u * (uint32_t)t) << 16,
                 sa + wave * 512 + lane * 8);
      asm volatile("s_waitcnt lgkmcnt(0)" ::: "memory");  // staged data in LDS
      __builtin_amdgcn_sched_barrier(0);
      if (lane == 0)
        __hip_atomic_store(&sflag[par][wave], want, __ATOMIC_RELAXED,
                           __HIP_MEMORY_SCOPE_WORKGROUP);

      float acc0 = 0.f, acc1 = 0.f, accO = 0.f;
      #pragma unroll
      for (int qi = 0; qi < 4; ++qi) {
        const int q = (wave + qi) & 3;
        if (qi > 0) lds_spin(&sflag[par][q], want);
        #pragma unroll
        for (int jj = 0; jj < 2; ++jj) {
          const int kb = (2 * q + jj) * 256 + lane * 4;
          const float4 a = *(const float4*)&sa[kb];
          const float4 g0 = gf0[qi * 2 + jj], g1 = gf1[qi * 2 + jj];
          const ushort4 wo = *(const ushort4*)(wflds + wave * DIM + kb);
          acc0 = fmaf(a.x, g0.x, acc0); acc1 = fmaf(a.x, g1.x, acc1);
          acc0 = fmaf(a.y, g0.y, acc0); acc1 = fmaf(a.y, g1.y, acc1);
          acc0 = fmaf(a.z, g0.z, acc0); acc1 = fmaf(a.z, g1.z, acc1);
          acc0 = fmaf(a.w, g0.w, acc0); acc1 = fmaf(a.w, g1.w, acc1);
          accO = fmaf(a.x, bf2f(wo.x), accO);
          accO = fmaf(a.y, bf2f(wo.y), accO);
          accO = fmaf(a.z, bf2f(wo.z), accO);
          accO = fmaf(a.w, bf2f(wo.w), accO);
        }
      }
      #pragma unroll
      for (int off = 32; off > 0; off >>= 1) {
        acc0 += __shfl_xor(acc0, off, 64);
        acc1 += __shfl_xor(acc1, off, 64);
        accO += __shfl_xor(accO, off, 64);
      }
      const uint32_t tag = 4u * (uint32_t)t + 1u;
      if (lane == 0) {
        const float v0 = acc0 + bf2f((uint16_t)(xcw & 0xFFFFu));
        const float v1 = acc1 + bf2f((uint16_t)(xcw >> 16));
        cstore64((u64*)a0b + myline, pack2(v0, v1, tag));  // own line, 8B
        if (t > 0)
          out[HID + (size_t)(t - 1) * HID + ocol] = accO + bo;  // outputs[t-1]
      }
      ++ph;
    }
    // ============ phases B,C,D: mid layers ============
    #pragma unroll
    for (int l = 1; l < 4; ++l) {
      const int par = (int)(ph & 1u);
      float* __restrict__ sa = sAct[par];
      const uint32_t want = ph + 1u;
      const uint32_t* src = (l == 1) ? a0b : ((l == 2) ? a1b : a2b);
      uint32_t* dst = (l == 1) ? a1b : ((l == 2) ? a2b : a3b);
      poll_stage(src, wave, lane, (4u * (uint32_t)t + (uint32_t)l) << 16,
                 sa + wave * 512 + lane * 8);
      asm volatile("s_waitcnt lgkmcnt(0)" ::: "memory");
      __builtin_amdgcn_sched_barrier(0);
      if (lane == 0)
        __hip_atomic_store(&sflag[par][wave], want, __ATOMIC_RELAXED,
                           __HIP_MEMORY_SCOPE_WORKGROUP);

      float acc0 = 0.f, acc1 = 0.f;
      const uint16_t* w0p = wlds + (((l - 1) * CPW + cidx0) * DIM);
      const uint16_t* w1p = w0p + DIM;
      #pragma unroll
      for (int qi = 0; qi < 4; ++qi) {
        const int q = (wave + qi) & 3;
        if (qi > 0) lds_spin(&sflag[par][q], want);
        #pragma unroll
        for (int jj = 0; jj < 2; ++jj) {
          const int kb = (2 * q + jj) * 256 + lane * 4;
          const float4  a  = *(const float4*)&sa[kb];
          const ushort4 wa = *(const ushort4*)(w0p + kb);
          const ushort4 wb = *(const ushort4*)(w1p + kb);
          acc0 = fmaf(a.x, bf2f(wa.x), acc0); acc1 = fmaf(a.x, bf2f(wb.x), acc1);
          acc0 = fmaf(a.y, bf2f(wa.y), acc0); acc1 = fmaf(a.y, bf2f(wb.y), acc1);
          acc0 = fmaf(a.z, bf2f(wa.z), acc0); acc1 = fmaf(a.z, bf2f(wb.z), acc1);
          acc0 = fmaf(a.w, bf2f(wa.w), acc0); acc1 = fmaf(a.w, bf2f(wb.w), acc1);
        }
      }
      #pragma unroll
      for (int off = 32; off > 0; off >>= 1) {
        acc0 += __shfl_xor(acc0, off, 64);
        acc1 += __shfl_xor(acc1, off, 64);
      }
      const uint32_t tag = 4u * (uint32_t)t + (uint32_t)l + 1u;
      if (lane == 0)
        cstore64((u64*)dst + myline,
                 pack2(acc0 + bm0[l - 1], acc1 + bm1[l - 1], tag));
      ++ph;
    }
  }

  // ============ epilogue: out_seq(SEQ-1) + final hidden ============
  {
    float* __restrict__ sa = sAct[ph & 1u];
    poll_stage(a3b, wave, lane, (4u * (uint32_t)SEQ) << 16,
               sa + wave * 512 + lane * 8);
    __syncthreads();
    float accO = 0.f, accH = 0.f;
    #pragma unroll
    for (int j = 0; j < 8; ++j) {
      const int kb = j * 256 + lane * 4;
      const float4  a  = *(const float4*)&sa[kb];
      const ushort4 wo = *(const ushort4*)(wflds + wave * DIM + kb);
      accO = fmaf(a.x, bf2f(wo.x), accO);
      accO = fmaf(a.y, bf2f(wo.y), accO);
      accO = fmaf(a.z, bf2f(wo.z), accO);
      accO = fmaf(a.w, bf2f(wo.w), accO);
      accH = fmaf(a.x, Wf[(size_t)(kb + 0) * DIM + ocol], accH);
      accH = fmaf(a.y, Wf[(size_t)(kb + 1) * DIM + ocol], accH);
      accH = fmaf(a.z, Wf[(size_t)(kb + 2) * DIM + ocol], accH);
      accH = fmaf(a.w, Wf[(size_t)(kb + 3) * DIM + ocol], accH);
    }
    #pragma unroll
    for (int off = 32; off > 0; off >>= 1) {
      accO += __shfl_xor(accO, off, 64);
      accH += __shfl_xor(accH, off, 64);
    }
    if (lane == 0) {
      out[HID + (size_t)(SEQ - 1) * HID + ocol] = accO + bo;  // outputs[SEQ-1]
      out[ocol] = accH + bfv[ocol];                           // final hidden
    }
  }
}

extern "C" void kernel_launch(void* const* d_in, const int* in_sizes, int n_in,
                              void* d_out, int out_size, void* d_ws, size_t ws_size,
                              hipStream_t stream) {
  (void)in_sizes; (void)n_in; (void)out_size; (void)ws_size;
  const float* x    = (const float*)d_in[0];
  const float* W0   = (const float*)d_in[1];
  const float* b0   = (const float*)d_in[2];
  const float* Wmid = (const float*)d_in[3];
  const float* bmid = (const float*)d_in[4];
  const float* Wf   = (const float*)d_in[5];
  const float* bfv  = (const float*)d_in[6];
  float* out = (float*)d_out;

  uint8_t* ws = (uint8_t*)d_ws;
  uint32_t* a0b = (uint32_t*)(ws + 0);
  uint32_t* a1b = (uint32_t*)(ws + 65536);
  uint32_t* a2b = (uint32_t*)(ws + 131072);
  uint32_t* a3b = (uint32_t*)(ws + 196608);
  uint16_t* xct = (uint16_t*)(ws + 262144);  // XC rows 8190,8191
  float*    hb  = (float*)(ws + 270336);
  float*    Gt  = (float*)(ws + 278528);     // 16 MB f32

  // reset tags: line-buffers zero => "a3 ready for t=0 with zeros"
  hipMemsetAsync(d_ws, 0, 262144, stream);

  // one-time folds (parallel GEMMs, ~1-2 ms total)
  k_hb<<<dim3(8), dim3(256), 0, stream>>>(W0, b0, bfv, hb);
  k_G<<<dim3(128, 128), dim3(16, 16), 0, stream>>>(W0, Wf, Gt);
  k_XC<<<dim3(128, 512), dim3(16, 16), 0, stream>>>(x, W0, b0, hb, out, xct);

  rnn_persist<<<dim3(NWG), dim3(256), 0, stream>>>(
      Wmid, bmid, Wf, bfv, out, a0b, a1b, a2b, a3b, Gt, xct);
}

// Round 19
// 139163.708 us; speedup vs baseline: 1.3359x; 1.3359x over previous
//
#include <hip/hip_runtime.h>
#include <hip/hip_bf16.h>
#include <stdint.h>

#define SEQ     8192
#define DIM     2048
#define HID     1024
#define NWG     256
#define CPW     8      // columns per workgroup (fused/mid layers)

typedef unsigned long long u64;
typedef __attribute__((ext_vector_type(4))) unsigned int u32x4;

// ===== Algebraic fold (R12) + chunked single-writer lines (R13) +
// arrival-order compute (R16) + 2-deep pipelined poll at SAFE request rate
// (R18) =====
//
// a0(t) = XC(t) + relu(a3(t-1)) @ G ;  a_{i+1} = relu(a_i)@Wmid_i + b
// outputs[t] = relu(a3(t))@WfO+bfO (phase A of step t+1, off critical path)
// G = Wf[:,:1024]@W0[1024:,:] (f32), XC = x@W0[:1024,:]+b0(+bf@W0h for t>0).
// 4 exchanges/step (algebraic minimum; ReLU blocks further folding).
//
// Buffers (R13/R16 layout, R17's spread-out layout REVERTED -- it tripled
// polled footprint and collapsed 1.8x): 256 chunks x 64 B; chunk c bytes
// 0..31 = WG c's 8 tagged u32 cols {bf16|tag<<16}, bytes 32..63 pad. One
// writer per line; waves publish via LDS sG gather, wave0 lanes 0..3 store
// one coalesced 32B chunk.
//
// R18 poll: R15's correctness-PROVEN single-asm-block 2-deep skeleton, but
// each sample set = 2x global_load_dwordx4 (2 requests, not 8 dwords):
// steady rate ~53 G req/s -- R13-class, 5x under the R15 collapse budget.
// dwordx4 needs sub-register compares -> sets live in explicitly clobbered
// quads v[40:47] (A) / v[48:55] (B); compares reference them literally;
// winner v_mov'd to SSA outputs after the final vmcnt(0). No compiler
// copies of in-flight regs can exist (all inside one asm block + clobbers).
// vmcnt invariant: queue = [priors..., S0, S1, T0, T1]; vmcnt(2) leaves the
// two NEWEST (other set) -> checked set fully retired regardless of priors.
//
// Arrival-order compute (R16, +4%): stage own quarter -> lgkmcnt(0) ->
// sflag[par][wave]=ph+1 -> FMA quarters own-first, lds_spin as needed.
// Safety chains unchanged from R16 (tag monotone >= check, 4-phase buffer
// reuse ordering, sAct/sflag parity guarded by the global tag chain).
//
// XC hosting: XC[t] in OUT at outputs-row t+2 (overwritten 12 phases after
// consumption, tag-chain ordered). Tail rows in ws.
// ws: 0:a0b 16384:a1b 32768:a2b 49152:a3b (memset=0 => a3 "ready for t=0"
// with zeros == H(-1)=0)  65536: XC tail  73728: hb  81920: Gt f32 (16MB)

__device__ __forceinline__ uint16_t f2bf(float f) {
  union { float f; uint32_t u; } v; v.f = f;
  uint32_t r = v.u + 0x7FFFu + ((v.u >> 16) & 1u);   // round-to-nearest-even
  return (uint16_t)(r >> 16);
}
__device__ __forceinline__ float bf2f(uint16_t u) {
  union { uint32_t u; float f; } v; v.u = ((uint32_t)u) << 16; return v.f;
}
__device__ __forceinline__ void cstore64(u64* p, u64 v) {
  __hip_atomic_store(p, v, __ATOMIC_RELAXED, __HIP_MEMORY_SCOPE_AGENT);
}
__device__ __forceinline__ u64 pack2(float v0, float v1, uint32_t tag) {
  const uint32_t w0 = (uint32_t)f2bf(v0) | (tag << 16);
  const uint32_t w1 = (uint32_t)f2bf(v1) | (tag << 16);
  return ((u64)w1 << 32) | (u64)w0;
}

// 2-deep pipelined poll of one 64B chunk (lane's 8 tagged u32, 32B).
// Sample sets in clobbered quads; cadence ~RT/2; 2 req/sample.
__device__ __forceinline__ void poll2_stage(const uint32_t* __restrict__ buf,
                                            int chunk, uint32_t thr,
                                            float* __restrict__ d) {
  uint32_t o0, o1, o2, o3, o4, o5, o6, o7;
  u64 sacc;
  const uint32_t* p = buf + (size_t)chunk * 16;
  asm volatile(
    "global_load_dwordx4 v[40:43], %[ad], off sc0 sc1\n\t"
    "global_load_dwordx4 v[44:47], %[ad], off offset:16 sc0 sc1\n\t"
    "global_load_dwordx4 v[48:51], %[ad], off sc0 sc1\n\t"
    "global_load_dwordx4 v[52:55], %[ad], off offset:16 sc0 sc1\n\t"
    "Lpoll%=:\n\t"
    "s_waitcnt vmcnt(2)\n\t"                 // set A (v40-47) retired
    "v_cmp_lt_u32 vcc, v40, %[thr]\n\t"
    "s_mov_b64 %[sa], vcc\n\t"
    "v_cmp_lt_u32 vcc, v41, %[thr]\n\t"
    "s_or_b64 %[sa], %[sa], vcc\n\t"
    "v_cmp_lt_u32 vcc, v42, %[thr]\n\t"
    "s_or_b64 %[sa], %[sa], vcc\n\t"
    "v_cmp_lt_u32 vcc, v43, %[thr]\n\t"
    "s_or_b64 %[sa], %[sa], vcc\n\t"
    "v_cmp_lt_u32 vcc, v44, %[thr]\n\t"
    "s_or_b64 %[sa], %[sa], vcc\n\t"
    "v_cmp_lt_u32 vcc, v45, %[thr]\n\t"
    "s_or_b64 %[sa], %[sa], vcc\n\t"
    "v_cmp_lt_u32 vcc, v46, %[thr]\n\t"
    "s_or_b64 %[sa], %[sa], vcc\n\t"
    "v_cmp_lt_u32 vcc, v47, %[thr]\n\t"
    "s_or_b64 %[sa], %[sa], vcc\n\t"         // SCC = any dword not ready
    "s_cbranch_scc0 LdoneA%=\n\t"
    "global_load_dwordx4 v[40:43], %[ad], off sc0 sc1\n\t"
    "global_load_dwordx4 v[44:47], %[ad], off offset:16 sc0 sc1\n\t"
    "s_waitcnt vmcnt(2)\n\t"                 // set B (v48-55) retired
    "v_cmp_lt_u32 vcc, v48, %[thr]\n\t"
    "s_mov_b64 %[sa], vcc\n\t"
    "v_cmp_lt_u32 vcc, v49, %[thr]\n\t"
    "s_or_b64 %[sa], %[sa], vcc\n\t"
    "v_cmp_lt_u32 vcc, v50, %[thr]\n\t"
    "s_or_b64 %[sa], %[sa], vcc\n\t"
    "v_cmp_lt_u32 vcc, v51, %[thr]\n\t"
    "s_or_b64 %[sa], %[sa], vcc\n\t"
    "v_cmp_lt_u32 vcc, v52, %[thr]\n\t"
    "s_or_b64 %[sa], %[sa], vcc\n\t"
    "v_cmp_lt_u32 vcc, v53, %[thr]\n\t"
    "s_or_b64 %[sa], %[sa], vcc\n\t"
    "v_cmp_lt_u32 vcc, v54, %[thr]\n\t"
    "s_or_b64 %[sa], %[sa], vcc\n\t"
    "v_cmp_lt_u32 vcc, v55, %[thr]\n\t"
    "s_or_b64 %[sa], %[sa], vcc\n\t"
    "s_cbranch_scc0 LdoneB%=\n\t"
    "global_load_dwordx4 v[48:51], %[ad], off sc0 sc1\n\t"
    "global_load_dwordx4 v[52:55], %[ad], off offset:16 sc0 sc1\n\t"
    "s_branch Lpoll%=\n\t"
    "LdoneB%=:\n\t"
    "s_waitcnt vmcnt(0)\n\t"                 // retire A' before writing v40-47
    "v_mov_b32 v40, v48\n\t"
    "v_mov_b32 v41, v49\n\t"
    "v_mov_b32 v42, v50\n\t"
    "v_mov_b32 v43, v51\n\t"
    "v_mov_b32 v44, v52\n\t"
    "v_mov_b32 v45, v53\n\t"
    "v_mov_b32 v46, v54\n\t"
    "v_mov_b32 v47, v55\n\t"
    "s_branch Lexit%=\n\t"
    "LdoneA%=:\n\t"
    "s_waitcnt vmcnt(0)\n\t"                 // retire outstanding B loads
    "Lexit%=:\n\t"
    "v_mov_b32 %[o0], v40\n\t"
    "v_mov_b32 %[o1], v41\n\t"
    "v_mov_b32 %[o2], v42\n\t"
    "v_mov_b32 %[o3], v43\n\t"
    "v_mov_b32 %[o4], v44\n\t"
    "v_mov_b32 %[o5], v45\n\t"
    "v_mov_b32 %[o6], v46\n\t"
    "v_mov_b32 %[o7], v47\n\t"
    : [o0]"=&v"(o0), [o1]"=&v"(o1), [o2]"=&v"(o2), [o3]"=&v"(o3),
      [o4]"=&v"(o4), [o5]"=&v"(o5), [o6]"=&v"(o6), [o7]"=&v"(o7),
      [sa]"=&s"(sacc)
    : [ad]"v"(p), [thr]"v"(thr)
    : "v40","v41","v42","v43","v44","v45","v46","v47",
      "v48","v49","v50","v51","v52","v53","v54","v55",
      "vcc","scc","memory");
  d[0] = fmaxf(__uint_as_float(o0 << 16), 0.f);   // relu(bf16->f32)
  d[1] = fmaxf(__uint_as_float(o1 << 16), 0.f);
  d[2] = fmaxf(__uint_as_float(o2 << 16), 0.f);
  d[3] = fmaxf(__uint_as_float(o3 << 16), 0.f);
  d[4] = fmaxf(__uint_as_float(o4 << 16), 0.f);
  d[5] = fmaxf(__uint_as_float(o5 << 16), 0.f);
  d[6] = fmaxf(__uint_as_float(o6 << 16), 0.f);
  d[7] = fmaxf(__uint_as_float(o7 << 16), 0.f);
}

// spin on an LDS quarter-flag until it reaches `want` (monotone)
__device__ __forceinline__ void lds_spin(uint32_t* f, uint32_t want) {
  while (__hip_atomic_load(f, __ATOMIC_RELAXED,
                           __HIP_MEMORY_SCOPE_WORKGROUP) < want) {}
  asm volatile("" ::: "memory");
  __builtin_amdgcn_sched_barrier(0);
}

// ---------------- precompute kernels (one-time, parallel) ----------------
__global__ void k_hb(const float* __restrict__ W0, const float* __restrict__ b0,
                     const float* __restrict__ bfv, float* __restrict__ hb) {
  const int j = blockIdx.x * 256 + threadIdx.x;
  float acc = b0[j];
  for (int m = 0; m < HID; ++m)
    acc = fmaf(bfv[m], W0[(size_t)(HID + m) * DIM + j], acc);
  hb[j] = acc;
}

__global__ void k_G(const float* __restrict__ W0, const float* __restrict__ Wf,
                    float* __restrict__ Gt) {
  const int j = blockIdx.x * 16 + threadIdx.x;     // a0 column
  const int k = blockIdx.y * 16 + threadIdx.y;     // a3 index
  float acc = 0.f;
  for (int m = 0; m < HID; ++m)
    acc = fmaf(Wf[(size_t)k * DIM + m], W0[(size_t)(HID + m) * DIM + j], acc);
  Gt[(size_t)j * DIM + k] = acc;
}

__global__ void k_XC(const float* __restrict__ x, const float* __restrict__ W0,
                     const float* __restrict__ b0, const float* __restrict__ hb,
                     float* __restrict__ out, uint16_t* __restrict__ xct) {
  const int j = blockIdx.x * 16 + threadIdx.x;
  const int t = blockIdx.y * 16 + threadIdx.y;
  float acc = 0.f;
  for (int m = 0; m < HID; ++m)
    acc = fmaf(x[(size_t)t * HID + m], W0[(size_t)m * DIM + j], acc);
  acc += (t > 0) ? hb[j] : b0[j];
  const uint16_t v = f2bf(acc);
  if (t <= SEQ - 3) ((uint16_t*)(out + HID + (size_t)(t + 2) * HID))[j] = v;
  else              xct[(size_t)(t - (SEQ - 2)) * DIM + j] = v;
}

// ---------------- persistent 4-phase recurrence kernel ----------------
__global__ void __launch_bounds__(256, 1)
rnn_persist(const float* __restrict__ Wmid, const float* __restrict__ bmid,
            const float* __restrict__ Wf, const float* __restrict__ bfv,
            float* __restrict__ out, uint32_t* __restrict__ a0b,
            uint32_t* __restrict__ a1b, uint32_t* __restrict__ a2b,
            uint32_t* __restrict__ a3b, const float* __restrict__ Gt,
            const uint16_t* __restrict__ xct)
{
  __shared__ uint16_t wlds[3 * CPW * DIM];   // Wmid 0..2 slices, 96 KiB
  __shared__ uint16_t wflds[4 * DIM];        // Wf out-col slice, 16 KiB
  __shared__ float    sAct[2][DIM];          // parity double-buffered, 16 KiB
  __shared__ u64      sG[2][4];              // parity gather slots (tagged)
  __shared__ uint32_t sflag[2][4];           // parity quarter-ready flags

  const int tid  = threadIdx.x;
  const int wg   = blockIdx.x;
  const int wave = tid >> 6;
  const int lane = tid & 63;

  const int cidx0 = wave * 2;
  const int col0  = wg * CPW + cidx0;        // fused/mid layer columns
  const int col1  = col0 + 1;
  const int ocol  = wg * 4 + wave;           // out_seq / hidden column

  // ---- stage Wmid slices (bf16) into LDS ----
  for (int i = tid; i < 3 * CPW * DIM; i += 256) {
    const int l = i >> 14;
    const int r = i & 16383;
    const int k = r >> 3;
    const int c = r & 7;
    wlds[(l * CPW + c) * DIM + k] =
        f2bf(Wmid[(size_t)l * DIM * DIM + (size_t)k * DIM + (wg * CPW + c)]);
  }
  // ---- stage Wf out-columns (4 per WG) into LDS ----
  for (int i = tid; i < 4 * DIM; i += 256) {
    const int w = i >> 11;
    const int k = i & 2047;
    wflds[w * DIM + k] = f2bf(Wf[(size_t)k * DIM + HID + wg * 4 + w]);
  }
  // ---- fused-layer G columns into registers, own-quarter-relative order:
  //      gf[qi*2+jj] covers k-block (2*((wave+qi)&3)+jj) (compile-time idx) --
  float4 gf0[8], gf1[8];
  #pragma unroll
  for (int qi = 0; qi < 4; ++qi) {
    const int q = (wave + qi) & 3;
    #pragma unroll
    for (int jj = 0; jj < 2; ++jj) {
      const int k = (2 * q + jj) * 256 + lane * 4;
      gf0[qi * 2 + jj] = *(const float4*)(Gt + (size_t)col0 * DIM + k);
      gf1[qi * 2 + jj] = *(const float4*)(Gt + (size_t)col1 * DIM + k);
    }
  }
  if (tid < 8) {
    sG[tid >> 2][tid & 3] = 0;
    sflag[tid >> 2][tid & 3] = 0;
  }
  __syncthreads();   // weights + slot init visible

  float bm0[3], bm1[3];
  #pragma unroll
  for (int l = 0; l < 3; ++l) {
    bm0[l] = bmid[l * DIM + col0];
    bm1[l] = bmid[l * DIM + col1];
  }
  const float bo = bfv[HID + ocol];

  uint32_t ph = 0;   // phase index = 4t + l

  for (int t = 0; t < SEQ; ++t) {
    // ============ phase A: fused layer + out_seq(t-1) ============
    {
      const int par = (int)(ph & 1u);
      float* __restrict__ sa = sAct[par];
      const uint32_t want = ph + 1u;
      const uint16_t* xcrow = (t <= SEQ - 3)
          ? (const uint16_t*)(out + HID + (size_t)(t + 2) * HID)
          : (xct + (size_t)(t - (SEQ - 2)) * DIM);
      const uint32_t xcw = *(const uint32_t*)(xcrow + col0);

      poll2_stage(a3b, wave * 64 + lane, (4u * (uint32_t)t) << 16,
                  sa + wave * 512 + lane * 8);
      asm volatile("s_waitcnt lgkmcnt(0)" ::: "memory");  // staged data in LDS
      __builtin_amdgcn_sched_barrier(0);
      if (lane == 0)
        __hip_atomic_store(&sflag[par][wave], want, __ATOMIC_RELAXED,
                           __HIP_MEMORY_SCOPE_WORKGROUP);

      float acc0 = 0.f, acc1 = 0.f, accO = 0.f;
      #pragma unroll
      for (int qi = 0; qi < 4; ++qi) {
        const int q = (wave + qi) & 3;
        if (qi > 0) lds_spin(&sflag[par][q], want);
        #pragma unroll
        for (int jj = 0; jj < 2; ++jj) {
          const int kb = (2 * q + jj) * 256 + lane * 4;
          const float4 a = *(const float4*)&sa[kb];
          const float4 g0 = gf0[qi * 2 + jj], g1 = gf1[qi * 2 + jj];
          const ushort4 wo = *(const ushort4*)(wflds + wave * DIM + kb);
          acc0 = fmaf(a.x, g0.x, acc0); acc1 = fmaf(a.x, g1.x, acc1);
          acc0 = fmaf(a.y, g0.y, acc0); acc1 = fmaf(a.y, g1.y, acc1);
          acc0 = fmaf(a.z, g0.z, acc0); acc1 = fmaf(a.z, g1.z, acc1);
          acc0 = fmaf(a.w, g0.w, acc0); acc1 = fmaf(a.w, g1.w, acc1);
          accO = fmaf(a.x, bf2f(wo.x), accO);
          accO = fmaf(a.y, bf2f(wo.y), accO);
          accO = fmaf(a.z, bf2f(wo.z), accO);
          accO = fmaf(a.w, bf2f(wo.w), accO);
        }
      }
      #pragma unroll
      for (int off = 32; off > 0; off >>= 1) {
        acc0 += __shfl_xor(acc0, off, 64);
        acc1 += __shfl_xor(acc1, off, 64);
        accO += __shfl_xor(accO, off, 64);
      }
      const uint32_t tag = 4u * (uint32_t)t + 1u;
      if (lane == 0) {
        const float v0 = acc0 + bf2f((uint16_t)(xcw & 0xFFFFu));
        const float v1 = acc1 + bf2f((uint16_t)(xcw >> 16));
        __hip_atomic_store(&sG[par][wave], pack2(v0, v1, tag),
                           __ATOMIC_RELAXED, __HIP_MEMORY_SCOPE_WORKGROUP);
        if (t > 0)
          out[HID + (size_t)(t - 1) * HID + ocol] = accO + bo;  // outputs[t-1]
      }
      if (wave == 0 && lane < 4) {
        const uint32_t thr = tag << 16;
        u64 pv;
        for (;;) {
          pv = __hip_atomic_load(&sG[par][lane], __ATOMIC_RELAXED,
                                 __HIP_MEMORY_SCOPE_WORKGROUP);
          if ((uint32_t)pv >= thr && (uint32_t)(pv >> 32) >= thr) break;
        }
        cstore64((u64*)a0b + wg * 8 + lane, pv);   // one 32B request, 1 line
      }
      ++ph;
    }
    // ============ phases B,C,D: mid layers ============
    #pragma unroll
    for (int l = 1; l < 4; ++l) {
      const int par = (int)(ph & 1u);
      float* __restrict__ sa = sAct[par];
      const uint32_t want = ph + 1u;
      const uint32_t* src = (l == 1) ? a0b : ((l == 2) ? a1b : a2b);
      uint32_t* dst = (l == 1) ? a1b : ((l == 2) ? a2b : a3b);
      poll2_stage(src, wave * 64 + lane,
                  (4u * (uint32_t)t + (uint32_t)l) << 16,
                  sa + wave * 512 + lane * 8);
      asm volatile("s_waitcnt lgkmcnt(0)" ::: "memory");
      __builtin_amdgcn_sched_barrier(0);
      if (lane == 0)
        __hip_atomic_store(&sflag[par][wave], want, __ATOMIC_RELAXED,
                           __HIP_MEMORY_SCOPE_WORKGROUP);

      float acc0 = 0.f, acc1 = 0.f;
      const uint16_t* w0p = wlds + (((l - 1) * CPW + cidx0) * DIM);
      const uint16_t* w1p = w0p + DIM;
      #pragma unroll
      for (int qi = 0; qi < 4; ++qi) {
        const int q = (wave + qi) & 3;
        if (qi > 0) lds_spin(&sflag[par][q], want);
        #pragma unroll
        for (int jj = 0; jj < 2; ++jj) {
          const int kb = (2 * q + jj) * 256 + lane * 4;
          const float4  a  = *(const float4*)&sa[kb];
          const ushort4 wa = *(const ushort4*)(w0p + kb);
          const ushort4 wb = *(const ushort4*)(w1p + kb);
          acc0 = fmaf(a.x, bf2f(wa.x), acc0); acc1 = fmaf(a.x, bf2f(wb.x), acc1);
          acc0 = fmaf(a.y, bf2f(wa.y), acc0); acc1 = fmaf(a.y, bf2f(wb.y), acc1);
          acc0 = fmaf(a.z, bf2f(wa.z), acc0); acc1 = fmaf(a.z, bf2f(wb.z), acc1);
          acc0 = fmaf(a.w, bf2f(wa.w), acc0); acc1 = fmaf(a.w, bf2f(wb.w), acc1);
        }
      }
      #pragma unroll
      for (int off = 32; off > 0; off >>= 1) {
        acc0 += __shfl_xor(acc0, off, 64);
        acc1 += __shfl_xor(acc1, off, 64);
      }
      const uint32_t tag = 4u * (uint32_t)t + (uint32_t)l + 1u;
      if (lane == 0) {
        __hip_atomic_store(&sG[par][wave],
                           pack2(acc0 + bm0[l - 1], acc1 + bm1[l - 1], tag),
                           __ATOMIC_RELAXED, __HIP_MEMORY_SCOPE_WORKGROUP);
      }
      if (wave == 0 && lane < 4) {
        const uint32_t thr = tag << 16;
        u64 pv;
        for (;;) {
          pv = __hip_atomic_load(&sG[par][lane], __ATOMIC_RELAXED,
                                 __HIP_MEMORY_SCOPE_WORKGROUP);
          if ((uint32_t)pv >= thr && (uint32_t)(pv >> 32) >= thr) break;
        }
        cstore64((u64*)dst + wg * 8 + lane, pv);
      }
      ++ph;
    }
  }

  // ============ epilogue: out_seq(SEQ-1) + final hidden ============
  {
    float* __restrict__ sa = sAct[ph & 1u];
    poll2_stage(a3b, wave * 64 + lane, (4u * (uint32_t)SEQ) << 16,
                sa + wave * 512 + lane * 8);
    __syncthreads();
    float accO = 0.f, accH = 0.f;
    #pragma unroll
    for (int j = 0; j < 8; ++j) {
      const int kb = j * 256 + lane * 4;
      const float4  a  = *(const float4*)&sa[kb];
      const ushort4 wo = *(const ushort4*)(wflds + wave * DIM + kb);
      accO = fmaf(a.x, bf2f(wo.x), accO);
      accO = fmaf(a.y, bf2f(wo.y), accO);
      accO = fmaf(a.z, bf2f(wo.z), accO);
      accO = fmaf(a.w, bf2f(wo.w), accO);
      accH = fmaf(a.x, Wf[(size_t)(kb + 0) * DIM + ocol], accH);
      accH = fmaf(a.y, Wf[(size_t)(kb + 1) * DIM + ocol], accH);
      accH = fmaf(a.z, Wf[(size_t)(kb + 2) * DIM + ocol], accH);
      accH = fmaf(a.w, Wf[(size_t)(kb + 3) * DIM + ocol], accH);
    }
    #pragma unroll
    for (int off = 32; off > 0; off >>= 1) {
      accO += __shfl_xor(accO, off, 64);
      accH += __shfl_xor(accH, off, 64);
    }
    if (lane == 0) {
      out[HID + (size_t)(SEQ - 1) * HID + ocol] = accO + bo;  // outputs[SEQ-1]
      out[ocol] = accH + bfv[ocol];                           // final hidden
    }
  }
}

extern "C" void kernel_launch(void* const* d_in, const int* in_sizes, int n_in,
                              void* d_out, int out_size, void* d_ws, size_t ws_size,
                              hipStream_t stream) {
  (void)in_sizes; (void)n_in; (void)out_size; (void)ws_size;
  const float* x    = (const float*)d_in[0];
  const float* W0   = (const float*)d_in[1];
  const float* b0   = (const float*)d_in[2];
  const float* Wmid = (const float*)d_in[3];
  const float* bmid = (const float*)d_in[4];
  const float* Wf   = (const float*)d_in[5];
  const float* bfv  = (const float*)d_in[6];
  float* out = (float*)d_out;

  uint8_t* ws = (uint8_t*)d_ws;
  uint32_t* a0b = (uint32_t*)(ws + 0);
  uint32_t* a1b = (uint32_t*)(ws + 16384);
  uint32_t* a2b = (uint32_t*)(ws + 32768);
  uint32_t* a3b = (uint32_t*)(ws + 49152);
  uint16_t* xct = (uint16_t*)(ws + 65536);   // XC rows 8190,8191
  float*    hb  = (float*)(ws + 73728);
  float*    Gt  = (float*)(ws + 81920);      // 16 MB f32

  // reset tags: chunked a-buffers zero => "a3 ready for t=0 with zeros"
  hipMemsetAsync(d_ws, 0, 65536, stream);

  // one-time folds (parallel GEMMs, ~1-2 ms total)
  k_hb<<<dim3(8), dim3(256), 0, stream>>>(W0, b0, bfv, hb);
  k_G<<<dim3(128, 128), dim3(16, 16), 0, stream>>>(W0, Wf, Gt);
  k_XC<<<dim3(128, 512), dim3(16, 16), 0, stream>>>(x, W0, b0, hb, out, xct);

  rnn_persist<<<dim3(NWG), dim3(256), 0, stream>>>(
      Wmid, bmid, Wf, bfv, out, a0b, a1b, a2b, a3b, Gt, xct);
}

// Round 20
// 107654.968 us; speedup vs baseline: 1.7269x; 1.2927x over previous
//
#include <hip/hip_runtime.h>
#include <hip/hip_bf16.h>
#include <stdint.h>

#define SEQ     8192
#define DIM     2048
#define HID     1024
#define NWG     256
#define CPW     8      // columns per workgroup (fused/mid layers)

typedef unsigned long long u64;
typedef __attribute__((ext_vector_type(4))) unsigned int u32x4;

// ===== FINAL: Algebraic fold (R12) + chunked single-writer lines (R13) +
// arrival-order compute (R16). Best measured config: 109.65 ms total.
//
// Closed levers (do not revisit):
//  - detect cadence: pipelined/faster polling falsified 3x (R11 neutral,
//    R15 -2.3x, R18 -31%). Poll pressure steals coherent-path service from
//    the publish stores it waits on; R16's s_sleep(1) is load-bearing.
//  - per-wave publish spreading (R17): 4x polled footprint, -1.8x.
//  - fine-grained flags/backoff/rings: all neutral (R8/R9/R10).
//
// a0(t) = XC(t) + relu(a3(t-1)) @ G ;  a_{i+1} = relu(a_i)@Wmid_i + b
// outputs[t] = relu(a3(t))@WfO+bfO (phase A of step t+1, off critical path)
// G = Wf[:,:1024]@W0[1024:,:] (f32), XC = x@W0[:1024,:]+b0(+bf@W0h for t>0).
// 4 exchanges/step (algebraic minimum; ReLU blocks further folding).
//
// Buffers: 256 chunks x 64 B; chunk c bytes 0..31 = WG c's 8 tagged u32 cols
// {bf16|tag<<16}, bytes 32..63 pad. ONE writer per line. Consumer lane L
// polls chunk (wave*64+L): 2x dwordx4 -> vmcnt(0)+sched_barrier -> check ->
// s_sleep(1).
//
// Arrival-order compute: stage own quarter -> lgkmcnt(0) ->
// sflag[par][wave]=ph+1 -> FMA quarters own-first, lds_spin as needed.
//
// Safety: tags monotone (max 4*8191+5 < 2^16); ready iff dword >= tag<<16
// (value bits cannot fake readiness). A wave's publish data-depends on its
// drained poll loads => observing a tag implies the producer finished
// reading its inputs. Buffer reuse at step t+1 is gated through the full
// 4-phase tag chain => happens-after every step-t read. sAct/sflag parity
// (period 2) guarded by the same global chain. LDS ops in-order per wave.
//
// XC hosting: XC[t] in OUT at outputs-row t+2 (overwritten 12 phases after
// consumption, tag-chain ordered). Tail rows in ws.
// ws: 0:a0b 16384:a1b 32768:a2b 49152:a3b (memset=0 => a3 "ready for t=0"
// with zeros == H(-1)=0)  65536: XC tail  73728: hb  81920: Gt f32 (16MB)

__device__ __forceinline__ uint16_t f2bf(float f) {
  union { float f; uint32_t u; } v; v.f = f;
  uint32_t r = v.u + 0x7FFFu + ((v.u >> 16) & 1u);   // round-to-nearest-even
  return (uint16_t)(r >> 16);
}
__device__ __forceinline__ float bf2f(uint16_t u) {
  union { uint32_t u; float f; } v; v.u = ((uint32_t)u) << 16; return v.f;
}
__device__ __forceinline__ void cstore64(u64* p, u64 v) {
  __hip_atomic_store(p, v, __ATOMIC_RELAXED, __HIP_MEMORY_SCOPE_AGENT);
}
__device__ __forceinline__ u64 pack2(float v0, float v1, uint32_t tag) {
  const uint32_t w0 = (uint32_t)f2bf(v0) | (tag << 16);
  const uint32_t w1 = (uint32_t)f2bf(v1) | (tag << 16);
  return ((u64)w1 << 32) | (u64)w0;
}
__device__ __forceinline__ u32x4 cload128(const void* p) {
  u32x4 r;
  asm volatile("global_load_dwordx4 %0, %1, off sc0 sc1"
               : "=v"(r) : "v"(p) : "memory");
  return r;
}
__device__ __forceinline__ void vm_drain() {
  asm volatile("s_waitcnt vmcnt(0)" ::: "memory");
  __builtin_amdgcn_sched_barrier(0);
}

// R5/R13-proven poll of one 64B chunk (this lane's own line): 2x dwordx4,
// drain, check, sleep. Decode (relu) into the LDS staging quarter.
__device__ __forceinline__ void poll_stage(const uint32_t* __restrict__ buf,
                                           int chunk, uint32_t thr,
                                           float* __restrict__ d) {
  const uint32_t* p = buf + (size_t)chunk * 16;
  u32x4 a, b;
  for (;;) {
    a = cload128(p);
    b = cload128(p + 4);
    vm_drain();
    bool ok = true;
    #pragma unroll
    for (int i = 0; i < 4; ++i) {
      ok &= (a[i] >= thr);
      ok &= (b[i] >= thr);
    }
    if (__all(ok)) break;
    __builtin_amdgcn_s_sleep(1);
  }
  #pragma unroll
  for (int i = 0; i < 4; ++i) {
    d[i]     = fmaxf(__uint_as_float(a[i] << 16), 0.f);   // relu(bf16->f32)
    d[4 + i] = fmaxf(__uint_as_float(b[i] << 16), 0.f);
  }
}

// spin on an LDS quarter-flag until it reaches `want` (monotone)
__device__ __forceinline__ void lds_spin(uint32_t* f, uint32_t want) {
  while (__hip_atomic_load(f, __ATOMIC_RELAXED,
                           __HIP_MEMORY_SCOPE_WORKGROUP) < want) {}
  asm volatile("" ::: "memory");
  __builtin_amdgcn_sched_barrier(0);
}

// ---------------- precompute kernels (one-time, parallel) ----------------
__global__ void k_hb(const float* __restrict__ W0, const float* __restrict__ b0,
                     const float* __restrict__ bfv, float* __restrict__ hb) {
  const int j = blockIdx.x * 256 + threadIdx.x;
  float acc = b0[j];
  for (int m = 0; m < HID; ++m)
    acc = fmaf(bfv[m], W0[(size_t)(HID + m) * DIM + j], acc);
  hb[j] = acc;
}

__global__ void k_G(const float* __restrict__ W0, const float* __restrict__ Wf,
                    float* __restrict__ Gt) {
  const int j = blockIdx.x * 16 + threadIdx.x;     // a0 column
  const int k = blockIdx.y * 16 + threadIdx.y;     // a3 index
  float acc = 0.f;
  for (int m = 0; m < HID; ++m)
    acc = fmaf(Wf[(size_t)k * DIM + m], W0[(size_t)(HID + m) * DIM + j], acc);
  Gt[(size_t)j * DIM + k] = acc;
}

__global__ void k_XC(const float* __restrict__ x, const float* __restrict__ W0,
                     const float* __restrict__ b0, const float* __restrict__ hb,
                     float* __restrict__ out, uint16_t* __restrict__ xct) {
  const int j = blockIdx.x * 16 + threadIdx.x;
  const int t = blockIdx.y * 16 + threadIdx.y;
  float acc = 0.f;
  for (int m = 0; m < HID; ++m)
    acc = fmaf(x[(size_t)t * HID + m], W0[(size_t)m * DIM + j], acc);
  acc += (t > 0) ? hb[j] : b0[j];
  const uint16_t v = f2bf(acc);
  if (t <= SEQ - 3) ((uint16_t*)(out + HID + (size_t)(t + 2) * HID))[j] = v;
  else              xct[(size_t)(t - (SEQ - 2)) * DIM + j] = v;
}

// ---------------- persistent 4-phase recurrence kernel ----------------
__global__ void __launch_bounds__(256, 1)
rnn_persist(const float* __restrict__ Wmid, const float* __restrict__ bmid,
            const float* __restrict__ Wf, const float* __restrict__ bfv,
            float* __restrict__ out, uint32_t* __restrict__ a0b,
            uint32_t* __restrict__ a1b, uint32_t* __restrict__ a2b,
            uint32_t* __restrict__ a3b, const float* __restrict__ Gt,
            const uint16_t* __restrict__ xct)
{
  __shared__ uint16_t wlds[3 * CPW * DIM];   // Wmid 0..2 slices, 96 KiB
  __shared__ uint16_t wflds[4 * DIM];        // Wf out-col slice, 16 KiB
  __shared__ float    sAct[2][DIM];          // parity double-buffered, 16 KiB
  __shared__ u64      sG[2][4];              // parity gather slots (tagged)
  __shared__ uint32_t sflag[2][4];           // parity quarter-ready flags

  const int tid  = threadIdx.x;
  const int wg   = blockIdx.x;
  const int wave = tid >> 6;
  const int lane = tid & 63;

  const int cidx0 = wave * 2;
  const int col0  = wg * CPW + cidx0;        // fused/mid layer columns
  const int col1  = col0 + 1;
  const int ocol  = wg * 4 + wave;           // out_seq / hidden column

  // ---- stage Wmid slices (bf16) into LDS ----
  for (int i = tid; i < 3 * CPW * DIM; i += 256) {
    const int l = i >> 14;
    const int r = i & 16383;
    const int k = r >> 3;
    const int c = r & 7;
    wlds[(l * CPW + c) * DIM + k] =
        f2bf(Wmid[(size_t)l * DIM * DIM + (size_t)k * DIM + (wg * CPW + c)]);
  }
  // ---- stage Wf out-columns (4 per WG) into LDS ----
  for (int i = tid; i < 4 * DIM; i += 256) {
    const int w = i >> 11;
    const int k = i & 2047;
    wflds[w * DIM + k] = f2bf(Wf[(size_t)k * DIM + HID + wg * 4 + w]);
  }
  // ---- fused-layer G columns into registers, own-quarter-relative order:
  //      gf[qi*2+jj] covers k-block (2*((wave+qi)&3)+jj) (compile-time idx) --
  float4 gf0[8], gf1[8];
  #pragma unroll
  for (int qi = 0; qi < 4; ++qi) {
    const int q = (wave + qi) & 3;
    #pragma unroll
    for (int jj = 0; jj < 2; ++jj) {
      const int k = (2 * q + jj) * 256 + lane * 4;
      gf0[qi * 2 + jj] = *(const float4*)(Gt + (size_t)col0 * DIM + k);
      gf1[qi * 2 + jj] = *(const float4*)(Gt + (size_t)col1 * DIM + k);
    }
  }
  if (tid < 8) {
    sG[tid >> 2][tid & 3] = 0;
    sflag[tid >> 2][tid & 3] = 0;
  }
  __syncthreads();   // weights + slot init visible

  float bm0[3], bm1[3];
  #pragma unroll
  for (int l = 0; l < 3; ++l) {
    bm0[l] = bmid[l * DIM + col0];
    bm1[l] = bmid[l * DIM + col1];
  }
  const float bo = bfv[HID + ocol];

  uint32_t ph = 0;   // phase index = 4t + l

  for (int t = 0; t < SEQ; ++t) {
    // ============ phase A: fused layer + out_seq(t-1) ============
    {
      const int par = (int)(ph & 1u);
      float* __restrict__ sa = sAct[par];
      const uint32_t want = ph + 1u;
      const uint16_t* xcrow = (t <= SEQ - 3)
          ? (const uint16_t*)(out + HID + (size_t)(t + 2) * HID)
          : (xct + (size_t)(t - (SEQ - 2)) * DIM);
      const uint32_t xcw = *(const uint32_t*)(xcrow + col0);

      poll_stage(a3b, wave * 64 + lane, (4u * (uint32_t)t) << 16,
                 sa + wave * 512 + lane * 8);
      asm volatile("s_waitcnt lgkmcnt(0)" ::: "memory");  // staged data in LDS
      __builtin_amdgcn_sched_barrier(0);
      if (lane == 0)
        __hip_atomic_store(&sflag[par][wave], want, __ATOMIC_RELAXED,
                           __HIP_MEMORY_SCOPE_WORKGROUP);

      float acc0 = 0.f, acc1 = 0.f, accO = 0.f;
      #pragma unroll
      for (int qi = 0; qi < 4; ++qi) {
        const int q = (wave + qi) & 3;
        if (qi > 0) lds_spin(&sflag[par][q], want);
        #pragma unroll
        for (int jj = 0; jj < 2; ++jj) {
          const int kb = (2 * q + jj) * 256 + lane * 4;
          const float4 a = *(const float4*)&sa[kb];
          const float4 g0 = gf0[qi * 2 + jj], g1 = gf1[qi * 2 + jj];
          const ushort4 wo = *(const ushort4*)(wflds + wave * DIM + kb);
          acc0 = fmaf(a.x, g0.x, acc0); acc1 = fmaf(a.x, g1.x, acc1);
          acc0 = fmaf(a.y, g0.y, acc0); acc1 = fmaf(a.y, g1.y, acc1);
          acc0 = fmaf(a.z, g0.z, acc0); acc1 = fmaf(a.z, g1.z, acc1);
          acc0 = fmaf(a.w, g0.w, acc0); acc1 = fmaf(a.w, g1.w, acc1);
          accO = fmaf(a.x, bf2f(wo.x), accO);
          accO = fmaf(a.y, bf2f(wo.y), accO);
          accO = fmaf(a.z, bf2f(wo.z), accO);
          accO = fmaf(a.w, bf2f(wo.w), accO);
        }
      }
      #pragma unroll
      for (int off = 32; off > 0; off >>= 1) {
        acc0 += __shfl_xor(acc0, off, 64);
        acc1 += __shfl_xor(acc1, off, 64);
        accO += __shfl_xor(accO, off, 64);
      }
      const uint32_t tag = 4u * (uint32_t)t + 1u;
      if (lane == 0) {
        const float v0 = acc0 + bf2f((uint16_t)(xcw & 0xFFFFu));
        const float v1 = acc1 + bf2f((uint16_t)(xcw >> 16));
        __hip_atomic_store(&sG[par][wave], pack2(v0, v1, tag),
                           __ATOMIC_RELAXED, __HIP_MEMORY_SCOPE_WORKGROUP);
        if (t > 0)
          out[HID + (size_t)(t - 1) * HID + ocol] = accO + bo;  // outputs[t-1]
      }
      if (wave == 0 && lane < 4) {
        const uint32_t thr = tag << 16;
        u64 pv;
        for (;;) {
          pv = __hip_atomic_load(&sG[par][lane], __ATOMIC_RELAXED,
                                 __HIP_MEMORY_SCOPE_WORKGROUP);
          if ((uint32_t)pv >= thr && (uint32_t)(pv >> 32) >= thr) break;
        }
        cstore64((u64*)a0b + wg * 8 + lane, pv);   // one 32B request, 1 line
      }
      ++ph;
    }
    // ============ phases B,C,D: mid layers ============
    #pragma unroll
    for (int l = 1; l < 4; ++l) {
      const int par = (int)(ph & 1u);
      float* __restrict__ sa = sAct[par];
      const uint32_t want = ph + 1u;
      const uint32_t* src = (l == 1) ? a0b : ((l == 2) ? a1b : a2b);
      uint32_t* dst = (l == 1) ? a1b : ((l == 2) ? a2b : a3b);
      poll_stage(src, wave * 64 + lane,
                 (4u * (uint32_t)t + (uint32_t)l) << 16,
                 sa + wave * 512 + lane * 8);
      asm volatile("s_waitcnt lgkmcnt(0)" ::: "memory");
      __builtin_amdgcn_sched_barrier(0);
      if (lane == 0)
        __hip_atomic_store(&sflag[par][wave], want, __ATOMIC_RELAXED,
                           __HIP_MEMORY_SCOPE_WORKGROUP);

      float acc0 = 0.f, acc1 = 0.f;
      const uint16_t* w0p = wlds + (((l - 1) * CPW + cidx0) * DIM);
      const uint16_t* w1p = w0p + DIM;
      #pragma unroll
      for (int qi = 0; qi < 4; ++qi) {
        const int q = (wave + qi) & 3;
        if (qi > 0) lds_spin(&sflag[par][q], want);
        #pragma unroll
        for (int jj = 0; jj < 2; ++jj) {
          const int kb = (2 * q + jj) * 256 + lane * 4;
          const float4  a  = *(const float4*)&sa[kb];
          const ushort4 wa = *(const ushort4*)(w0p + kb);
          const ushort4 wb = *(const ushort4*)(w1p + kb);
          acc0 = fmaf(a.x, bf2f(wa.x), acc0); acc1 = fmaf(a.x, bf2f(wb.x), acc1);
          acc0 = fmaf(a.y, bf2f(wa.y), acc0); acc1 = fmaf(a.y, bf2f(wb.y), acc1);
          acc0 = fmaf(a.z, bf2f(wa.z), acc0); acc1 = fmaf(a.z, bf2f(wb.z), acc1);
          acc0 = fmaf(a.w, bf2f(wa.w), acc0); acc1 = fmaf(a.w, bf2f(wb.w), acc1);
        }
      }
      #pragma unroll
      for (int off = 32; off > 0; off >>= 1) {
        acc0 += __shfl_xor(acc0, off, 64);
        acc1 += __shfl_xor(acc1, off, 64);
      }
      const uint32_t tag = 4u * (uint32_t)t + (uint32_t)l + 1u;
      if (lane == 0) {
        __hip_atomic_store(&sG[par][wave],
                           pack2(acc0 + bm0[l - 1], acc1 + bm1[l - 1], tag),
                           __ATOMIC_RELAXED, __HIP_MEMORY_SCOPE_WORKGROUP);
      }
      if (wave == 0 && lane < 4) {
        const uint32_t thr = tag << 16;
        u64 pv;
        for (;;) {
          pv = __hip_atomic_load(&sG[par][lane], __ATOMIC_RELAXED,
                                 __HIP_MEMORY_SCOPE_WORKGROUP);
          if ((uint32_t)pv >= thr && (uint32_t)(pv >> 32) >= thr) break;
        }
        cstore64((u64*)dst + wg * 8 + lane, pv);
      }
      ++ph;
    }
  }

  // ============ epilogue: out_seq(SEQ-1) + final hidden ============
  {
    float* __restrict__ sa = sAct[ph & 1u];
    poll_stage(a3b, wave * 64 + lane, (4u * (uint32_t)SEQ) << 16,
               sa + wave * 512 + lane * 8);
    __syncthreads();
    float accO = 0.f, accH = 0.f;
    #pragma unroll
    for (int j = 0; j < 8; ++j) {
      const int kb = j * 256 + lane * 4;
      const float4  a  = *(const float4*)&sa[kb];
      const ushort4 wo = *(const ushort4*)(wflds + wave * DIM + kb);
      accO = fmaf(a.x, bf2f(wo.x), accO);
      accO = fmaf(a.y, bf2f(wo.y), accO);
      accO = fmaf(a.z, bf2f(wo.z), accO);
      accO = fmaf(a.w, bf2f(wo.w), accO);
      accH = fmaf(a.x, Wf[(size_t)(kb + 0) * DIM + ocol], accH);
      accH = fmaf(a.y, Wf[(size_t)(kb + 1) * DIM + ocol], accH);
      accH = fmaf(a.z, Wf[(size_t)(kb + 2) * DIM + ocol], accH);
      accH = fmaf(a.w, Wf[(size_t)(kb + 3) * DIM + ocol], accH);
    }
    #pragma unroll
    for (int off = 32; off > 0; off >>= 1) {
      accO += __shfl_xor(accO, off, 64);
      accH += __shfl_xor(accH, off, 64);
    }
    if (lane == 0) {
      out[HID + (size_t)(SEQ - 1) * HID + ocol] = accO + bo;  // outputs[SEQ-1]
      out[ocol] = accH + bfv[ocol];                           // final hidden
    }
  }
}

extern "C" void kernel_launch(void* const* d_in, const int* in_sizes, int n_in,
                              void* d_out, int out_size, void* d_ws, size_t ws_size,
                              hipStream_t stream) {
  (void)in_sizes; (void)n_in; (void)out_size; (void)ws_size;
  const float* x    = (const float*)d_in[0];
  const float* W0   = (const float*)d_in[1];
  const float* b0   = (const float*)d_in[2];
  const float* Wmid = (const float*)d_in[3];
  const float* bmid = (const float*)d_in[4];
  const float* Wf   = (const float*)d_in[5];
  const float* bfv  = (const float*)d_in[6];
  float* out = (float*)d_out;

  uint8_t* ws = (uint8_t*)d_ws;
  uint32_t* a0b = (uint32_t*)(ws + 0);
  uint32_t* a1b = (uint32_t*)(ws + 16384);
  uint32_t* a2b = (uint32_t*)(ws + 32768);
  uint32_t* a3b = (uint32_t*)(ws + 49152);
  uint16_t* xct = (uint16_t*)(ws + 65536);   // XC rows 8190,8191
  float*    hb  = (float*)(ws + 73728);
  float*    Gt  = (float*)(ws + 81920);      // 16 MB f32

  // reset tags: chunked a-buffers zero => "a3 ready for t=0 with zeros"
  hipMemsetAsync(d_ws, 0, 65536, stream);

  // one-time folds (parallel GEMMs, ~1-2 ms total)
  k_hb<<<dim3(8), dim3(256), 0, stream>>>(W0, b0, bfv, hb);
  k_G<<<dim3(128, 128), dim3(16, 16), 0, stream>>>(W0, Wf, Gt);
  k_XC<<<dim3(128, 512), dim3(16, 16), 0, stream>>>(x, W0, b0, hb, out, xct);

  rnn_persist<<<dim3(NWG), dim3(256), 0, stream>>>(
      Wmid, bmid, Wf, bfv, out, a0b, a1b, a2b, a3b, Gt, xct);
}